// Round 1
// baseline (508.535 us; speedup 1.0000x reference)
//
#include <hip/hip_runtime.h>
#include <math.h>

static constexpr int Bb = 4;
static constexpr int Nn = 512;
static constexpr int Dd = 1024;
static constexpr int Ee = 8;
static constexpr int Hh = 4096;
static constexpr float CAP = 4.0f;   // float(int(1.0 * B))
static constexpr float EPS = 1e-6f;

// ---------------- K1: gating (one wave per token) ----------------
__global__ __launch_bounds__(256) void k_gate(
    const float* __restrict__ x, const float* __restrict__ wg,
    const float* __restrict__ bg, int* __restrict__ top,
    float* __restrict__ gate0)
{
    __shared__ float swg[Ee * Dd];  // transposed [e][d] -> conflict-free reads
    const int tid = threadIdx.x;
    for (int i = tid; i < Dd * Ee; i += 256) {
        int d = i >> 3, e = i & 7;
        swg[e * Dd + d] = wg[i];
    }
    __syncthreads();
    const int lane = tid & 63;
    const int tok = blockIdx.x * 4 + (tid >> 6);   // 0..2047
    const float* xr = x + (size_t)tok * Dd;
    float acc[Ee];
#pragma unroll
    for (int e = 0; e < Ee; ++e) acc[e] = 0.f;
    for (int d = lane; d < Dd; d += 64) {
        float xv = xr[d];
#pragma unroll
        for (int e = 0; e < Ee; ++e) acc[e] += xv * swg[e * Dd + d];
    }
#pragma unroll
    for (int e = 0; e < Ee; ++e) {
        float v = acc[e];
#pragma unroll
        for (int off = 32; off > 0; off >>= 1) v += __shfl_xor(v, off, 64);
        acc[e] = v + bg[e];
    }
    if (lane == 0) {
        int best = 0;
        float bv = acc[0];
#pragma unroll
        for (int e = 1; e < Ee; ++e)
            if (acc[e] > bv) { bv = acc[e]; best = e; }   // strict > = first-max, jnp.argmax
        top[tok] = best;
        const int n = tok & (Nn - 1);
        if (n < 8) {
            const int b = tok >> 9;
            float m = acc[0];
#pragma unroll
            for (int e = 1; e < Ee; ++e) m = fmaxf(m, acc[e]);
            float s = 0.f;
#pragma unroll
            for (int e = 0; e < Ee; ++e) s += expf(acc[e] - m);
            gate0[b * 8 + n] = expf(acc[0] - m) / s;   // softmax prob of expert 0
        }
    }
}

// ---------------- K2: gate_scores + loss (tiny, 1 block) ----------------
__global__ __launch_bounds__(64) void k_score(
    const int* __restrict__ top, const float* __restrict__ gate0,
    float* __restrict__ gs, float* __restrict__ loss_out)
{
    __shared__ int smask[Bb];
    const int tid = threadIdx.x;
    if (tid < Bb) smask[tid] = 0;
    __syncthreads();
    for (int i = tid; i < Bb * Nn; i += 64) {
        atomicOr(&smask[i >> 9], 1 << top[i]);
    }
    __syncthreads();
    if (tid == 0) {
        float imp[8], ld[8], gsl[32];
        for (int n = 0; n < 8; ++n) {
            float mv[4];
            float den = 0.f;
            for (int b = 0; b < 4; ++b) {
                float g = ((smask[b] >> n) & 1) ? gate0[b * 8 + n] : 0.f;
                mv[b] = g;
                den += g;
            }
            den += EPS;
            float s = 0.f, cnt = 0.f;
            for (int b = 0; b < 4; ++b) {
                float v = mv[b] / den * CAP;
                gsl[b * 8 + n] = v;
                s += v;
                if (v > 0.f) cnt += 1.f;
            }
            imp[n] = s;
            ld[n] = cnt;
        }
        for (int i = 0; i < 32; ++i) gs[i] = gsl[i];
        // cv^2 over [N,E]=4096 entries, all zero except the 8 slots (n<8, e=0)
        const float M = (float)(Nn * Ee);
        float si = 0.f, sl = 0.f;
        for (int n = 0; n < 8; ++n) { si += imp[n]; sl += ld[n]; }
        const float mi = si / M, ml = sl / M;
        float di = 0.f, dl = 0.f;
        for (int n = 0; n < 8; ++n) {
            di += (imp[n] - mi) * (imp[n] - mi);
            dl += (ld[n] - ml) * (ld[n] - ml);
        }
        di += (M - 8.f) * mi * mi;
        dl += (M - 8.f) * ml * ml;
        const float vi = di / (M - 1.f), vl = dl / (M - 1.f);
        *loss_out = vi / (mi * mi + 1e-10f) + vl / (ml * ml + 1e-10f);
    }
}

// ---------------- K3a: expert-0 first GEMM + exact GELU ----------------
// grid (64 h-chunks of 64, 4 token-groups of 8), 128 threads
__global__ __launch_bounds__(128) void k_ffn1(
    const float* __restrict__ x, const float* __restrict__ w1,
    const float* __restrict__ b1, float* __restrict__ hbuf)
{
    __shared__ float xs[8][Dd + 1];   // +1 pad: kills 4-way bank conflict on xs[j][d]
    const int tid = threadIdx.x;
    const int hc = blockIdx.x;
    const int tg = blockIdx.y;
    for (int i = tid; i < 8 * Dd; i += 128) {
        int tl = i >> 10, d = i & (Dd - 1);
        int t = tg * 8 + tl;
        int b = t >> 3, n = t & 7;
        xs[tl][d] = x[((size_t)(b * Nn + n)) * Dd + d];
    }
    __syncthreads();
    const int j = tid >> 4;           // token lane 0..7
    const int hq = tid & 15;
    const int h = hc * 64 + hq * 4;
    float4 acc = make_float4(0.f, 0.f, 0.f, 0.f);
    const float* w1c = w1 + h;        // expert 0: w1[0][d][h] = w1[d*Hh + h]
#pragma unroll 4
    for (int d = 0; d < Dd; ++d) {
        float4 w = *(const float4*)(w1c + (size_t)d * Hh);
        float xv = xs[j][d];
        acc.x += xv * w.x; acc.y += xv * w.y;
        acc.z += xv * w.z; acc.w += xv * w.w;
    }
    const int t = tg * 8 + j;
    float4 o;
    float* op = &o.x;
    const float* ap = &acc.x;
#pragma unroll
    for (int k = 0; k < 4; ++k) {
        float v = ap[k] + b1[h + k];
        op[k] = 0.5f * v * (1.f + erff(v * 0.70710678118654752440f));  // exact gelu
    }
    *(float4*)(hbuf + (size_t)t * Hh + h) = o;
}

// ---------------- K3b: expert-0 second GEMM, split-K over H ----------------
// grid (16 d-chunks of 64, 4 token-groups, 4 k-chunks of 1024), 128 threads
__global__ __launch_bounds__(128) void k_ffn2(
    const float* __restrict__ hbuf, const float* __restrict__ w2,
    float* __restrict__ acc2)
{
    __shared__ float hs[8][1024 + 1];
    const int tid = threadIdx.x;
    const int dc = blockIdx.x;
    const int tg = blockIdx.y;
    const int kc = blockIdx.z;
    for (int i = tid; i < 8 * 1024; i += 128) {
        int tl = i >> 10, hh = i & 1023;
        int t = tg * 8 + tl;
        hs[tl][hh] = hbuf[(size_t)t * Hh + kc * 1024 + hh];
    }
    __syncthreads();
    const int j = tid >> 4;
    const int dq = tid & 15;
    const int d = dc * 64 + dq * 4;
    float4 acc = make_float4(0.f, 0.f, 0.f, 0.f);
    const float* w2c = w2 + (size_t)(kc * 1024) * Dd + d;  // expert 0: w2[h*Dd + d]
#pragma unroll 4
    for (int hh = 0; hh < 1024; ++hh) {
        float4 w = *(const float4*)(w2c + (size_t)hh * Dd);
        float xv = hs[j][hh];
        acc.x += xv * w.x; acc.y += xv * w.y;
        acc.z += xv * w.z; acc.w += xv * w.w;
    }
    const int t = tg * 8 + j;
    float* dst = acc2 + (size_t)t * Dd + d;
    atomicAdd(dst + 0, acc.x);
    atomicAdd(dst + 1, acc.y);
    atomicAdd(dst + 2, acc.z);
    atomicAdd(dst + 3, acc.w);
}

// ---------------- K3c: final output (zeros for n>=8) ----------------
// grid 2048 (one row each), 256 threads (float4 per thread)
__global__ __launch_bounds__(256) void k_out(
    const float* __restrict__ acc2, const float* __restrict__ b2,
    const float* __restrict__ gs, float* __restrict__ out)
{
    const int row = blockIdx.x;          // b*512 + n
    const int d = threadIdx.x * 4;
    const int n = row & (Nn - 1);
    float4 o = make_float4(0.f, 0.f, 0.f, 0.f);
    if (n < 8) {
        const int b = row >> 9;
        const int t = b * 8 + n;
        const float g = gs[t];
        float4 a = *(const float4*)(acc2 + (size_t)t * Dd + d);
        float4 bb = *(const float4*)(b2 + d);   // expert 0: b2[0][d]
        o.x = g * (a.x + bb.x);
        o.y = g * (a.y + bb.y);
        o.z = g * (a.z + bb.z);
        o.w = g * (a.w + bb.w);
    }
    *(float4*)(out + (size_t)row * Dd + d) = o;
}

extern "C" void kernel_launch(void* const* d_in, const int* in_sizes, int n_in,
                              void* d_out, int out_size, void* d_ws, size_t ws_size,
                              hipStream_t stream) {
    const float* x  = (const float*)d_in[0];
    const float* wg = (const float*)d_in[1];
    const float* bg = (const float*)d_in[2];
    const float* w1 = (const float*)d_in[3];
    const float* b1 = (const float*)d_in[4];
    const float* w2 = (const float*)d_in[5];
    const float* b2 = (const float*)d_in[6];
    float* out = (float*)d_out;

    // ws layout (floats): [0,2048) top_idx(int) | [2048,2080) gate0 |
    // [2080,2112) gs | [4096, 4096+131072) hbuf | then acc2[32768]
    float* wsf   = (float*)d_ws;
    int*   top   = (int*)d_ws;
    float* gate0 = wsf + 2048;
    float* gs    = wsf + 2080;
    float* hbuf  = wsf + 4096;
    float* acc2  = wsf + 4096 + 32 * Hh;

    hipMemsetAsync(acc2, 0, 32 * Dd * sizeof(float), stream);
    k_gate<<<dim3(Bb * Nn / 4), dim3(256), 0, stream>>>(x, wg, bg, top, gate0);
    k_score<<<dim3(1), dim3(64), 0, stream>>>(top, gate0, gs, out + (out_size - 1));
    k_ffn1<<<dim3(64, 4), dim3(128), 0, stream>>>(x, w1, b1, hbuf);
    k_ffn2<<<dim3(16, 4, 4), dim3(128), 0, stream>>>(hbuf, w2, acc2);
    k_out<<<dim3(Bb * Nn), dim3(256), 0, stream>>>(acc2, b2, gs, out);
}

// Round 2
// 300.862 us; speedup vs baseline: 1.6903x; 1.6903x over previous
//
#include <hip/hip_runtime.h>
#include <math.h>

static constexpr int Bb = 4;
static constexpr int Nn = 512;
static constexpr int Dd = 1024;
static constexpr int Ee = 8;
static constexpr int Hh = 4096;
static constexpr float CAP = 4.0f;   // float(int(1.0 * B))
static constexpr float EPS = 1e-6f;

// ---------------- K1: gating (one wave per token) + xT extraction ----------------
__global__ __launch_bounds__(256) void k_gate(
    const float* __restrict__ x, const float* __restrict__ wg,
    const float* __restrict__ bg, int* __restrict__ top,
    float* __restrict__ gate0, float* __restrict__ xT)
{
    __shared__ float swg[Ee * Dd];  // transposed [e][d] -> conflict-free reads
    const int tid = threadIdx.x;
    for (int i = tid; i < Dd * Ee; i += 256) {
        int d = i >> 3, e = i & 7;
        swg[e * Dd + d] = wg[i];
    }
    __syncthreads();
    const int lane = tid & 63;
    const int tok = blockIdx.x * 4 + (tid >> 6);   // 0..2047
    const float* xr = x + (size_t)tok * Dd;
    float acc[Ee];
#pragma unroll
    for (int e = 0; e < Ee; ++e) acc[e] = 0.f;
    for (int d = lane; d < Dd; d += 64) {
        float xv = xr[d];
#pragma unroll
        for (int e = 0; e < Ee; ++e) acc[e] += xv * swg[e * Dd + d];
    }
#pragma unroll
    for (int e = 0; e < Ee; ++e) {
        float v = acc[e];
#pragma unroll
        for (int off = 32; off > 0; off >>= 1) v += __shfl_xor(v, off, 64);
        acc[e] = v + bg[e];
    }
    const int n = tok & (Nn - 1);
    const int b = tok >> 9;
    if (n < 8) {
        // extract this token's x row into xT[d][32] (transposed, token-minor)
        const int t32 = b * 8 + n;
        for (int d = lane; d < Dd; d += 64) xT[d * 32 + t32] = xr[d];
    }
    if (lane == 0) {
        int best = 0;
        float bv = acc[0];
#pragma unroll
        for (int e = 1; e < Ee; ++e)
            if (acc[e] > bv) { bv = acc[e]; best = e; }   // strict > = first-max, jnp.argmax
        top[tok] = best;
        if (n < 8) {
            float m = acc[0];
#pragma unroll
            for (int e = 1; e < Ee; ++e) m = fmaxf(m, acc[e]);
            float s = 0.f;
#pragma unroll
            for (int e = 0; e < Ee; ++e) s += expf(acc[e] - m);
            gate0[b * 8 + n] = expf(acc[0] - m) / s;   // softmax prob of expert 0
        }
    }
}

// ---------------- K2: gate_scores + loss (tiny, 1 block) ----------------
__global__ __launch_bounds__(64) void k_score(
    const int* __restrict__ top, const float* __restrict__ gate0,
    float* __restrict__ gs, float* __restrict__ loss_out)
{
    __shared__ int smask[Bb];
    const int tid = threadIdx.x;
    if (tid < Bb) smask[tid] = 0;
    __syncthreads();
    for (int i = tid; i < Bb * Nn; i += 64) {
        atomicOr(&smask[i >> 9], 1 << top[i]);
    }
    __syncthreads();
    if (tid == 0) {
        float imp[8], ld[8], gsl[32];
        for (int n = 0; n < 8; ++n) {
            float mv[4];
            float den = 0.f;
            for (int b = 0; b < 4; ++b) {
                float g = ((smask[b] >> n) & 1) ? gate0[b * 8 + n] : 0.f;
                mv[b] = g;
                den += g;
            }
            den += EPS;
            float s = 0.f, cnt = 0.f;
            for (int b = 0; b < 4; ++b) {
                float v = mv[b] / den * CAP;
                gsl[b * 8 + n] = v;
                s += v;
                if (v > 0.f) cnt += 1.f;
            }
            imp[n] = s;
            ld[n] = cnt;
        }
        for (int i = 0; i < 32; ++i) gs[i] = gsl[i];
        const float M = (float)(Nn * Ee);
        float si = 0.f, sl = 0.f;
        for (int n = 0; n < 8; ++n) { si += imp[n]; sl += ld[n]; }
        const float mi = si / M, ml = sl / M;
        float di = 0.f, dl = 0.f;
        for (int n = 0; n < 8; ++n) {
            di += (imp[n] - mi) * (imp[n] - mi);
            dl += (ld[n] - ml) * (ld[n] - ml);
        }
        di += (M - 8.f) * mi * mi;
        dl += (M - 8.f) * ml * ml;
        const float vi = di / (M - 1.f), vl = dl / (M - 1.f);
        *loss_out = vi / (mi * mi + 1e-10f) + vl / (ml * ml + 1e-10f);
    }
}

// ---------------- K3: FFN1 GEMM, split-K. grid (16 h-chunks, 16 k-splits) ----------------
// thread -> one h column, 32 token accumulators. Weights read once, coalesced.
// x broadcast via wave-uniform loads (scalar pipe).
__global__ __launch_bounds__(256) void k_ffn1(
    const float* __restrict__ w1, const float* __restrict__ xT,
    float* __restrict__ p1)
{
    const int tid = threadIdx.x;
    const int h = blockIdx.x * 256 + tid;
    const int k0 = blockIdx.y * 64;          // KC = 64
    const float* w = w1 + (size_t)k0 * Hh + h;   // expert 0: w1[d][h]
    const float* xk = xT + k0 * 32;
    float acc[32];
#pragma unroll
    for (int t = 0; t < 32; ++t) acc[t] = 0.f;
    for (int k = 0; k < 64; ++k) {
        float wv = *w;
        w += Hh;
#pragma unroll
        for (int t = 0; t < 32; ++t) acc[t] = fmaf(xk[t], wv, acc[t]);
        xk += 32;
    }
    float* o = p1 + ((size_t)blockIdx.y * 32) * Hh + h;
#pragma unroll
    for (int t = 0; t < 32; ++t) { *o = acc[t]; o += Hh; }
}

// ---------------- K4: reduce p1 + bias + exact GELU -> hT[hh][32] ----------------
__global__ __launch_bounds__(256) void k_h(
    const float* __restrict__ p1, const float* __restrict__ b1,
    float* __restrict__ hT)
{
    const int idx = blockIdx.x * 256 + threadIdx.x;  // 131072 total
    const int hh = idx & (Hh - 1);
    const int t = idx >> 12;
    float s = b1[hh];                                 // expert 0: b1[0][hh]
#pragma unroll
    for (int q = 0; q < 16; ++q)
        s += p1[((size_t)(q * 32 + t)) * Hh + hh];
    hT[(size_t)hh * 32 + t] = 0.5f * s * (1.f + erff(s * 0.70710678118654752440f));
}

// ---------------- K5: FFN2 GEMM, split-K. grid (4 d-chunks, 64 k-splits) ----------------
__global__ __launch_bounds__(256) void k_ffn2(
    const float* __restrict__ w2, const float* __restrict__ hT,
    float* __restrict__ p2)
{
    const int tid = threadIdx.x;
    const int d = blockIdx.x * 256 + tid;
    const int k0 = blockIdx.y * 64;          // KC = 64
    const float* w = w2 + (size_t)k0 * Dd + d;   // expert 0: w2[h][d]
    const float* hk = hT + k0 * 32;
    float acc[32];
#pragma unroll
    for (int t = 0; t < 32; ++t) acc[t] = 0.f;
    for (int k = 0; k < 64; ++k) {
        float wv = *w;
        w += Dd;
#pragma unroll
        for (int t = 0; t < 32; ++t) acc[t] = fmaf(hk[t], wv, acc[t]);
        hk += 32;
    }
    float* o = p2 + ((size_t)blockIdx.y * 32) * Dd + d;
#pragma unroll
    for (int t = 0; t < 32; ++t) { *o = acc[t]; o += Dd; }
}

// ---------------- K6: final output (zeros for n>=8), reduce p2 ----------------
__global__ __launch_bounds__(256) void k_out(
    const float* __restrict__ p2, const float* __restrict__ b2,
    const float* __restrict__ gs, float* __restrict__ out)
{
    const int row = blockIdx.x;          // b*512 + n
    const int d4 = threadIdx.x * 4;
    const int n = row & (Nn - 1);
    float4 o = make_float4(0.f, 0.f, 0.f, 0.f);
    if (n < 8) {
        const int b = row >> 9;
        const int t = b * 8 + n;
        const float g = gs[t];
        float4 a = make_float4(0.f, 0.f, 0.f, 0.f);
        const float* p = p2 + (size_t)t * Dd + d4;
#pragma unroll 8
        for (int s = 0; s < 64; ++s) {
            float4 v = *(const float4*)p;
            p += (size_t)32 * Dd;
            a.x += v.x; a.y += v.y; a.z += v.z; a.w += v.w;
        }
        float4 bb = *(const float4*)(b2 + d4);   // expert 0: b2[0][d]
        o.x = g * (a.x + bb.x);
        o.y = g * (a.y + bb.y);
        o.z = g * (a.z + bb.z);
        o.w = g * (a.w + bb.w);
    }
    *(float4*)(out + (size_t)row * Dd + d4) = o;
}

extern "C" void kernel_launch(void* const* d_in, const int* in_sizes, int n_in,
                              void* d_out, int out_size, void* d_ws, size_t ws_size,
                              hipStream_t stream) {
    const float* x  = (const float*)d_in[0];
    const float* wg = (const float*)d_in[1];
    const float* bg = (const float*)d_in[2];
    const float* w1 = (const float*)d_in[3];
    const float* b1 = (const float*)d_in[4];
    const float* w2 = (const float*)d_in[5];
    const float* b2 = (const float*)d_in[6];
    float* out = (float*)d_out;

    // ws layout (float offsets):
    // [0,2048)       top (int)
    // [2048,2080)    gate0
    // [2080,2112)    gs
    // [4096,36864)   xT[1024][32]
    // [36864,167936) hT[4096][32]
    // [167936,2265088)  p1[16][32][4096]
    // [2265088,4362240) p2[64][32][1024]   (total ~17.5 MB)
    float* wsf   = (float*)d_ws;
    int*   top   = (int*)d_ws;
    float* gate0 = wsf + 2048;
    float* gs    = wsf + 2080;
    float* xT    = wsf + 4096;
    float* hT    = wsf + 36864;
    float* p1    = wsf + 167936;
    float* p2    = wsf + 2265088;

    k_gate<<<dim3(Bb * Nn / 4), dim3(256), 0, stream>>>(x, wg, bg, top, gate0, xT);
    k_score<<<dim3(1), dim3(64), 0, stream>>>(top, gate0, gs, out + (out_size - 1));
    k_ffn1<<<dim3(16, 16), dim3(256), 0, stream>>>(w1, xT, p1);
    k_h<<<dim3(512), dim3(256), 0, stream>>>(p1, b1, hT);
    k_ffn2<<<dim3(4, 64), dim3(256), 0, stream>>>(w2, hT, p2);
    k_out<<<dim3(Bb * Nn), dim3(256), 0, stream>>>(p2, b2, gs, out);
}

// Round 3
// 300.309 us; speedup vs baseline: 1.6934x; 1.0018x over previous
//
#include <hip/hip_runtime.h>
#include <math.h>

static constexpr int Bb = 4;
static constexpr int Nn = 512;
static constexpr int Dd = 1024;
static constexpr int Ee = 8;
static constexpr int Hh = 4096;
static constexpr float CAP = 4.0f;   // float(int(1.0 * B))
static constexpr float EPS = 1e-6f;

static constexpr int P1S = 32;   // ffn1 k-splits (KC=32)
static constexpr int P2S = 64;   // ffn2 k-splits (KC=64)

// ---------------- K1: gating (one wave per token) + xT extraction + smask ----------------
__global__ __launch_bounds__(256) void k_gate(
    const float* __restrict__ x, const float* __restrict__ wg,
    const float* __restrict__ bg, int* __restrict__ smask,
    float* __restrict__ gate0, float* __restrict__ xT)
{
    __shared__ float swg[Ee * 1028];  // [e][d], row pad +4 -> conflict-free staging
    const int tid = threadIdx.x;
    for (int i = tid; i < Dd * Ee; i += 256) {
        int d = i >> 3, e = i & 7;
        swg[e * 1028 + d] = wg[i];
    }
    __syncthreads();
    const int lane = tid & 63;
    const int tok = blockIdx.x * 4 + (tid >> 6);   // 0..2047
    const float* xr = x + (size_t)tok * Dd;
    float acc[Ee];
#pragma unroll
    for (int e = 0; e < Ee; ++e) acc[e] = 0.f;
#pragma unroll
    for (int j = 0; j < 4; ++j) {
        const int d0 = j * 256 + lane * 4;
        float4 xv = *(const float4*)(xr + d0);
#pragma unroll
        for (int e = 0; e < Ee; ++e) {
            float4 wv = *(const float4*)(&swg[e * 1028 + d0]);
            acc[e] = fmaf(xv.x, wv.x, acc[e]);
            acc[e] = fmaf(xv.y, wv.y, acc[e]);
            acc[e] = fmaf(xv.z, wv.z, acc[e]);
            acc[e] = fmaf(xv.w, wv.w, acc[e]);
        }
    }
#pragma unroll
    for (int e = 0; e < Ee; ++e) {
        float v = acc[e];
#pragma unroll
        for (int off = 32; off > 0; off >>= 1) v += __shfl_xor(v, off, 64);
        acc[e] = v + bg[e];
    }
    const int n = tok & (Nn - 1);
    const int b = tok >> 9;
    if (n < 8) {
        // extract this token's x row into xT[d][32] (token-minor)
        const int t32 = b * 8 + n;
        for (int d = lane; d < Dd; d += 64) xT[d * 32 + t32] = xr[d];
    }
    if (lane == 0) {
        int best = 0;
        float bv = acc[0];
#pragma unroll
        for (int e = 1; e < Ee; ++e)
            if (acc[e] > bv) { bv = acc[e]; best = e; }   // strict > = first-max, jnp.argmax
        atomicOr(&smask[b], 1 << best);
        if (n < 8) {
            float m = acc[0];
#pragma unroll
            for (int e = 1; e < Ee; ++e) m = fmaxf(m, acc[e]);
            float s = 0.f;
#pragma unroll
            for (int e = 0; e < Ee; ++e) s += expf(acc[e] - m);
            gate0[b * 8 + n] = expf(acc[0] - m) / s;   // softmax prob of expert 0
        }
    }
}

// ---------------- K2: gate_scores + loss (tiny, 1 wave) ----------------
__global__ __launch_bounds__(64) void k_score(
    const int* __restrict__ smask, const float* __restrict__ gate0,
    float* __restrict__ gs, float* __restrict__ loss_out)
{
    if (threadIdx.x == 0) {
        float imp[8], ld[8], gsl[32];
        for (int n = 0; n < 8; ++n) {
            float mv[4];
            float den = 0.f;
            for (int b = 0; b < 4; ++b) {
                float g = ((smask[b] >> n) & 1) ? gate0[b * 8 + n] : 0.f;
                mv[b] = g;
                den += g;
            }
            den += EPS;
            float s = 0.f, cnt = 0.f;
            for (int b = 0; b < 4; ++b) {
                float v = mv[b] / den * CAP;
                gsl[b * 8 + n] = v;
                s += v;
                if (v > 0.f) cnt += 1.f;
            }
            imp[n] = s;
            ld[n] = cnt;
        }
        for (int i = 0; i < 32; ++i) gs[i] = gsl[i];
        const float M = (float)(Nn * Ee);
        float si = 0.f, sl = 0.f;
        for (int n = 0; n < 8; ++n) { si += imp[n]; sl += ld[n]; }
        const float mi = si / M, ml = sl / M;
        float di = 0.f, dl = 0.f;
        for (int n = 0; n < 8; ++n) {
            di += (imp[n] - mi) * (imp[n] - mi);
            dl += (ld[n] - ml) * (ld[n] - ml);
        }
        di += (M - 8.f) * mi * mi;
        dl += (M - 8.f) * ml * ml;
        const float vi = di / (M - 1.f), vl = dl / (M - 1.f);
        *loss_out = vi / (mi * mi + 1e-10f) + vl / (ml * ml + 1e-10f);
    }
}

// ---------------- K3: FFN1 GEMM. grid (8 h-chunks of 512, 32 k-splits of 32) ----------------
// thread -> float2 of h, 32 token accumulators. Weights batched 16-deep in registers
// (16 outstanding loads/thread); activations via broadcast ds_read_b128.
__global__ __launch_bounds__(256) void k_ffn1(
    const float* __restrict__ w1, const float* __restrict__ xT,
    float* __restrict__ p1)
{
    __shared__ float xs[32 * 32];      // [k][t] chunk
    const int tid = threadIdx.x;
    {
        float4 v = *(const float4*)(xT + blockIdx.y * (32 * 32) + tid * 4);
        *(float4*)(xs + tid * 4) = v;
    }
    __syncthreads();
    const int h = blockIdx.x * 512 + tid * 2;
    const int k0 = blockIdx.y * 32;
    const float* wp = w1 + (size_t)k0 * Hh + h;   // expert 0: w1[d][h]
    float2 acc[32];
#pragma unroll
    for (int t = 0; t < 32; ++t) acc[t] = make_float2(0.f, 0.f);
#pragma unroll
    for (int half = 0; half < 2; ++half) {
        float2 wbuf[16];
#pragma unroll
        for (int kk = 0; kk < 16; ++kk)
            wbuf[kk] = *(const float2*)(wp + (size_t)(half * 16 + kk) * Hh);
#pragma unroll
        for (int kk = 0; kk < 16; ++kk) {
            const float4* xrow = (const float4*)(xs + (half * 16 + kk) * 32);
            const float2 w = wbuf[kk];
#pragma unroll
            for (int t4 = 0; t4 < 8; ++t4) {
                float4 xv = xrow[t4];
                acc[t4 * 4 + 0].x = fmaf(xv.x, w.x, acc[t4 * 4 + 0].x);
                acc[t4 * 4 + 0].y = fmaf(xv.x, w.y, acc[t4 * 4 + 0].y);
                acc[t4 * 4 + 1].x = fmaf(xv.y, w.x, acc[t4 * 4 + 1].x);
                acc[t4 * 4 + 1].y = fmaf(xv.y, w.y, acc[t4 * 4 + 1].y);
                acc[t4 * 4 + 2].x = fmaf(xv.z, w.x, acc[t4 * 4 + 2].x);
                acc[t4 * 4 + 2].y = fmaf(xv.z, w.y, acc[t4 * 4 + 2].y);
                acc[t4 * 4 + 3].x = fmaf(xv.w, w.x, acc[t4 * 4 + 3].x);
                acc[t4 * 4 + 3].y = fmaf(xv.w, w.y, acc[t4 * 4 + 3].y);
            }
        }
    }
    float* o = p1 + ((size_t)blockIdx.y * 32) * Hh + h;
#pragma unroll
    for (int t = 0; t < 32; ++t) { *(float2*)o = acc[t]; o += Hh; }
}

// ---------------- K4: reduce p1 + bias + exact GELU -> hT[hh][32] ----------------
__global__ __launch_bounds__(256) void k_h(
    const float* __restrict__ p1, const float* __restrict__ b1,
    float* __restrict__ hT)
{
    const int idx = blockIdx.x * 256 + threadIdx.x;  // 131072 total
    const int hh = idx & (Hh - 1);
    const int t = idx >> 12;
    float s = b1[hh];                                 // expert 0: b1[0][hh]
#pragma unroll
    for (int q = 0; q < P1S; ++q)
        s += p1[((size_t)(q * 32 + t)) * Hh + hh];
    hT[(size_t)hh * 32 + t] = 0.5f * s * (1.f + erff(s * 0.70710678118654752440f));
}

// ---------------- K5: FFN2 GEMM. grid (4 d-chunks of 256, 64 k-splits of 64) ----------------
__global__ __launch_bounds__(256) void k_ffn2(
    const float* __restrict__ w2, const float* __restrict__ hT,
    float* __restrict__ p2)
{
    __shared__ float hs[64 * 32];      // [k][t] chunk
    const int tid = threadIdx.x;
    {
        float4 v0 = *(const float4*)(hT + blockIdx.y * (64 * 32) + tid * 8);
        float4 v1 = *(const float4*)(hT + blockIdx.y * (64 * 32) + tid * 8 + 4);
        *(float4*)(hs + tid * 8) = v0;
        *(float4*)(hs + tid * 8 + 4) = v1;
    }
    __syncthreads();
    const int d = blockIdx.x * 256 + tid;
    const int k0 = blockIdx.y * 64;
    const float* wp = w2 + (size_t)k0 * Dd + d;   // expert 0: w2[h][d]
    float acc[32];
#pragma unroll
    for (int t = 0; t < 32; ++t) acc[t] = 0.f;
#pragma unroll
    for (int q = 0; q < 4; ++q) {
        float wbuf[16];
#pragma unroll
        for (int kk = 0; kk < 16; ++kk)
            wbuf[kk] = wp[(size_t)(q * 16 + kk) * Dd];
#pragma unroll
        for (int kk = 0; kk < 16; ++kk) {
            const float4* xrow = (const float4*)(hs + (q * 16 + kk) * 32);
            const float w = wbuf[kk];
#pragma unroll
            for (int t4 = 0; t4 < 8; ++t4) {
                float4 xv = xrow[t4];
                acc[t4 * 4 + 0] = fmaf(xv.x, w, acc[t4 * 4 + 0]);
                acc[t4 * 4 + 1] = fmaf(xv.y, w, acc[t4 * 4 + 1]);
                acc[t4 * 4 + 2] = fmaf(xv.z, w, acc[t4 * 4 + 2]);
                acc[t4 * 4 + 3] = fmaf(xv.w, w, acc[t4 * 4 + 3]);
            }
        }
    }
    float* o = p2 + ((size_t)blockIdx.y * 32) * Dd + d;
#pragma unroll
    for (int t = 0; t < 32; ++t) { *o = acc[t]; o += Dd; }
}

// ---------------- K6: final output (zeros for n>=8), reduce p2 ----------------
__global__ __launch_bounds__(256) void k_out(
    const float* __restrict__ p2, const float* __restrict__ b2,
    const float* __restrict__ gs, float* __restrict__ out)
{
    const int row = blockIdx.x;          // b*512 + n
    const int d4 = threadIdx.x * 4;
    const int n = row & (Nn - 1);
    float4 o = make_float4(0.f, 0.f, 0.f, 0.f);
    if (n < 8) {
        const int b = row >> 9;
        const int t = b * 8 + n;
        const float g = gs[t];
        float4 a = make_float4(0.f, 0.f, 0.f, 0.f);
        const float* p = p2 + (size_t)t * Dd + d4;
#pragma unroll 8
        for (int s = 0; s < P2S; ++s) {
            float4 v = *(const float4*)p;
            p += (size_t)32 * Dd;
            a.x += v.x; a.y += v.y; a.z += v.z; a.w += v.w;
        }
        float4 bb = *(const float4*)(b2 + d4);   // expert 0: b2[0][d]
        o.x = g * (a.x + bb.x);
        o.y = g * (a.y + bb.y);
        o.z = g * (a.z + bb.z);
        o.w = g * (a.w + bb.w);
    }
    *(float4*)(out + (size_t)row * Dd + d4) = o;
}

extern "C" void kernel_launch(void* const* d_in, const int* in_sizes, int n_in,
                              void* d_out, int out_size, void* d_ws, size_t ws_size,
                              hipStream_t stream) {
    const float* x  = (const float*)d_in[0];
    const float* wg = (const float*)d_in[1];
    const float* bg = (const float*)d_in[2];
    const float* w1 = (const float*)d_in[3];
    const float* b1 = (const float*)d_in[4];
    const float* w2 = (const float*)d_in[5];
    const float* b2 = (const float*)d_in[6];
    float* out = (float*)d_out;

    // ws layout (float offsets):
    // [0,4)          smask (int, must be zeroed)
    // [64,96)        gate0
    // [128,160)      gs
    // [256,33024)    xT[1024][32]
    // [36864,167936) hT[4096][32]
    // [167936, +32*32*4096)   p1  (16 MB)
    // [4362240, +64*32*1024)  p2  (8 MB)
    float* wsf   = (float*)d_ws;
    int*   smask = (int*)d_ws;
    float* gate0 = wsf + 64;
    float* gs    = wsf + 128;
    float* xT    = wsf + 256;
    float* hT    = wsf + 36864;
    float* p1    = wsf + 167936;
    float* p2    = wsf + 4362240;

    hipMemsetAsync(smask, 0, 4 * sizeof(int), stream);
    k_gate<<<dim3(Bb * Nn / 4), dim3(256), 0, stream>>>(x, wg, bg, smask, gate0, xT);
    k_score<<<dim3(1), dim3(64), 0, stream>>>(smask, gate0, gs, out + (out_size - 1));
    k_ffn1<<<dim3(8, P1S), dim3(256), 0, stream>>>(w1, xT, p1);
    k_h<<<dim3(512), dim3(256), 0, stream>>>(p1, b1, hT);
    k_ffn2<<<dim3(4, P2S), dim3(256), 0, stream>>>(w2, hT, p2);
    k_out<<<dim3(Bb * Nn), dim3(256), 0, stream>>>(p2, b2, gs, out);
}